// Round 1
// baseline (8307.961 us; speedup 1.0000x reference)
//
#include <hip/hip_runtime.h>

#define N_NODES 100000
#define N_EDGES 50000
#define NNZ     800000
#define C       256

// K1: out[0 : N*C] = x0 (copy); out[N*C : (N+E)*C] = 0  (x_1 accumulator)
__global__ void init_kernel(const float* __restrict__ x0, float* __restrict__ out) {
    long long i = (long long)blockIdx.x * blockDim.x + threadIdx.x;  // float4 index
    const long long n_node4 = (long long)N_NODES * C / 4;
    const long long n_tot4  = (long long)(N_NODES + N_EDGES) * C / 4;
    float4* o4 = (float4*)out;
    if (i < n_node4) {
        o4[i] = ((const float4*)x0)[i];
    } else if (i < n_tot4) {
        o4[i] = make_float4(0.f, 0.f, 0.f, 0.f);
    }
}

// One wave (64 lanes) per incidence j: gather one 256-float row from src
// (indexed by src_idx[j]) and atomicAdd it into dst row dst_idx[j].
// Lane l handles channels [4l, 4l+4).
__global__ void scatter_add_kernel(const float* __restrict__ src,
                                   const int* __restrict__ src_idx,
                                   const int* __restrict__ dst_idx,
                                   float* __restrict__ dst) {
    int j    = blockIdx.x * (blockDim.x >> 6) + (threadIdx.x >> 6);
    int lane = threadIdx.x & 63;
    if (j >= NNZ) return;
    int s = src_idx[j];
    int d = dst_idx[j];
    const float4 v = *(const float4*)(src + (long long)s * C + lane * 4);
    float* dp = dst + (long long)d * C + lane * 4;
    atomicAdd(dp + 0, v.x);
    atomicAdd(dp + 1, v.y);
    atomicAdd(dp + 2, v.z);
    atomicAdd(dp + 3, v.w);
}

// K4: in-place row GEMM: row = row @ W.T + b.
// One block per node row. Row staged to LDS, sync, then each thread t
// computes out[n][t] = b[t] + dot(row, W[t][:]).
// In-place is safe: the only global read of `row` happens before the sync.
__global__ void gin_gemm_kernel(const float* __restrict__ W,
                                const float* __restrict__ b,
                                float* __restrict__ out) {
    int n = blockIdx.x;
    int t = threadIdx.x;
    __shared__ float xs[C];
    float* row = out + (long long)n * C;
    xs[t] = row[t];
    __syncthreads();
    float acc = b[t];
    const float* wrow = W + t * C;
#pragma unroll 8
    for (int k = 0; k < C; k += 4) {
        float4 xv = *(const float4*)(xs + k);     // LDS b128
        float4 wv = *(const float4*)(wrow + k);   // global float4, L1-streamed per row
        acc = fmaf(xv.x, wv.x, acc);
        acc = fmaf(xv.y, wv.y, acc);
        acc = fmaf(xv.z, wv.z, acc);
        acc = fmaf(xv.w, wv.w, acc);
    }
    row[t] = acc;
}

extern "C" void kernel_launch(void* const* d_in, const int* in_sizes, int n_in,
                              void* d_out, int out_size, void* d_ws, size_t ws_size,
                              hipStream_t stream) {
    const float* x0       = (const float*)d_in[0];
    const int*   node_idx = (const int*)d_in[1];
    const int*   edge_idx = (const int*)d_in[2];
    const float* W        = (const float*)d_in[3];
    const float* b        = (const float*)d_in[4];
    float* out = (float*)d_out;
    float* x1  = out + (size_t)N_NODES * C;

    // K1: out <- [x0 | 0]
    long long tot4 = (long long)(N_NODES + N_EDGES) * C / 4;
    init_kernel<<<(int)((tot4 + 255) / 256), 256, 0, stream>>>(x0, out);

    // K2: vertex->edge: x1[edge_idx[j]] += x0[node_idx[j]]
    int jobs_per_block = 256 / 64;
    int grid = (NNZ + jobs_per_block - 1) / jobs_per_block;
    scatter_add_kernel<<<grid, 256, 0, stream>>>(x0, node_idx, edge_idx, x1);

    // K3: edge->vertex: out[node_idx[j]] += x1[edge_idx[j]]  (out holds x0 -> becomes x0+m)
    scatter_add_kernel<<<grid, 256, 0, stream>>>(x1, edge_idx, node_idx, out);

    // K4: out_row = (x0+m) @ W.T + b, in place
    gin_gemm_kernel<<<N_NODES, 256, 0, stream>>>(W, b, out);
}

// Round 2
// 915.330 us; speedup vs baseline: 9.0765x; 9.0765x over previous
//
#include <hip/hip_runtime.h>

#define N_NODES 100000
#define N_EDGES 50000
#define NNZ     800000
#define C       256

typedef short  bf16x8 __attribute__((ext_vector_type(8)));
typedef float  f32x4  __attribute__((ext_vector_type(4)));

static __device__ __forceinline__ unsigned short f2bf(float f) {
    unsigned int u = __float_as_uint(f);
    u += 0x7FFF + ((u >> 16) & 1);   // round-to-nearest-even
    return (unsigned short)(u >> 16);
}

// ---------------- sort-free CSR construction ----------------

__global__ void hist_kernel(const int* __restrict__ node_idx,
                            const int* __restrict__ edge_idx,
                            int* __restrict__ cnt_n, int* __restrict__ cnt_e) {
    int j = blockIdx.x * blockDim.x + threadIdx.x;
    if (j >= NNZ) return;
    atomicAdd(&cnt_n[node_idx[j]], 1);
    atomicAdd(&cnt_e[edge_idx[j]], 1);
}

// one-block exclusive scan; off has n+1 entries
__global__ void scan_exclusive(const int* __restrict__ cnt, int* __restrict__ off, int n) {
    __shared__ int wsum[16];
    __shared__ int s_carry;
    const int t = threadIdx.x;
    const int lane = t & 63;
    const int w = t >> 6;
    if (t == 0) s_carry = 0;
    __syncthreads();
    for (int base = 0; base < n; base += 1024) {
        int idx = base + t;
        int v = (idx < n) ? cnt[idx] : 0;
        int incl = v;
#pragma unroll
        for (int s = 1; s < 64; s <<= 1) {
            int u = __shfl_up(incl, s, 64);
            if (lane >= s) incl += u;
        }
        if (lane == 63) wsum[w] = incl;
        __syncthreads();
        if (w == 0 && lane < 16) {
            int sv = wsum[lane];
            int si = sv;
#pragma unroll
            for (int s = 1; s < 16; s <<= 1) {
                int u = __shfl_up(si, s, 64);
                if (lane >= s) si += u;
            }
            wsum[lane] = si - sv;   // exclusive wave offset
        }
        __syncthreads();
        int excl = s_carry + wsum[w] + incl - v;
        if (idx < n) off[idx] = excl;
        __syncthreads();
        if (t == 1023) s_carry = excl + v;
        __syncthreads();
    }
    if (t == 0) off[n] = s_carry;
}

__global__ void build_perm(const int* __restrict__ node_idx,
                           const int* __restrict__ edge_idx,
                           int* __restrict__ cur_e, int* __restrict__ cur_n,
                           int* __restrict__ perm_e, int* __restrict__ perm_n) {
    int j = blockIdx.x * blockDim.x + threadIdx.x;
    if (j >= NNZ) return;
    int ni = node_idx[j], ei = edge_idx[j];
    int pe = atomicAdd(&cur_e[ei], 1);
    perm_e[pe] = ni;            // source node row for this edge segment
    int pn = atomicAdd(&cur_n[ni], 1);
    perm_n[pn] = ei;            // source edge row for this node segment
}

// ---------------- segment-sum pulls (no atomics) ----------------

// x1[e] = sum_{k in seg(e)} x0[perm_e[k]]   (one wave per edge)
__global__ void pull_edge(const float* __restrict__ x0,
                          const int* __restrict__ off, const int* __restrict__ perm,
                          float* __restrict__ x1) {
    int e = blockIdx.x * (blockDim.x >> 6) + (threadIdx.x >> 6);
    int lane = threadIdx.x & 63;
    if (e >= N_EDGES) return;
    int s0 = off[e], s1 = off[e + 1];
    float ax = 0.f, ay = 0.f, az = 0.f, aw = 0.f;
    for (int k = s0; k < s1; k++) {
        int r = perm[k];
        const float4 v = *(const float4*)(x0 + (long long)r * C + lane * 4);
        ax += v.x; ay += v.y; az += v.z; aw += v.w;
    }
    float4 o = make_float4(ax, ay, az, aw);
    *(float4*)(x1 + (long long)e * C + lane * 4) = o;
}

// xm_bf16[n] = bf16( x0[n] + sum_{k in seg(n)} x1[perm_n[k]] )  (EPS=0)
__global__ void pull_node(const float* __restrict__ x0, const float* __restrict__ x1,
                          const int* __restrict__ off, const int* __restrict__ perm,
                          unsigned short* __restrict__ xm) {
    int n = blockIdx.x * (blockDim.x >> 6) + (threadIdx.x >> 6);
    int lane = threadIdx.x & 63;
    if (n >= N_NODES) return;
    int s0 = off[n], s1 = off[n + 1];
    const float4 x = *(const float4*)(x0 + (long long)n * C + lane * 4);
    float ax = x.x, ay = x.y, az = x.z, aw = x.w;
    for (int k = s0; k < s1; k++) {
        int r = perm[k];
        const float4 v = *(const float4*)(x1 + (long long)r * C + lane * 4);
        ax += v.x; ay += v.y; az += v.z; aw += v.w;
    }
    ushort4 o;
    o.x = f2bf(ax); o.y = f2bf(ay); o.z = f2bf(az); o.w = f2bf(aw);
    *(ushort4*)(xm + (long long)n * C + lane * 4) = o;
}

__global__ void wconvert(const float* __restrict__ W, unsigned short* __restrict__ Wb) {
    int i = blockIdx.x * blockDim.x + threadIdx.x;   // 16384 threads, 4 elems each
    const float4 v = ((const float4*)W)[i];
    ushort4 o;
    o.x = f2bf(v.x); o.y = f2bf(v.y); o.z = f2bf(v.z); o.w = f2bf(v.w);
    ((ushort4*)Wb)[i] = o;
}

// ---------------- MFMA GEMM: out = xm @ W^T + b ----------------
// One wave computes 16 rows x 256 cols. A-frag: lane holds xm[row0+(lane&15)][k + q*8 .. +8].
// B = W^T (KxN), B-frag: lane holds B[k+q*8+j][lane&15 of tile] = W[16t+(lane&15)][k+q*8+j]
// -> contiguous 16B from row-major W. C/D (m89): col=lane&15 (N), row=q*4+reg (M).
__global__ void mfma_gemm(const unsigned short* __restrict__ xm,
                          const unsigned short* __restrict__ Wb,
                          const float* __restrict__ bias,
                          float* __restrict__ out) {
    int wave = blockIdx.x * (blockDim.x >> 6) + (threadIdx.x >> 6);
    int lane = threadIdx.x & 63;
    int row0 = wave * 16;
    if (row0 >= N_NODES) return;
    const int m = lane & 15;
    const int q = lane >> 4;
    f32x4 acc[16];
#pragma unroll
    for (int t = 0; t < 16; t++) acc[t] = (f32x4){0.f, 0.f, 0.f, 0.f};

    const unsigned short* arow = xm + (long long)(row0 + m) * C + q * 8;
    const unsigned short* brow = Wb + m * C + q * 8;
#pragma unroll
    for (int k = 0; k < C; k += 32) {
        bf16x8 a = *(const bf16x8*)(arow + k);
#pragma unroll
        for (int t = 0; t < 16; t++) {
            bf16x8 b = *(const bf16x8*)(brow + t * 16 * C + k);
            acc[t] = __builtin_amdgcn_mfma_f32_16x16x32_bf16(a, b, acc[t], 0, 0, 0);
        }
    }
#pragma unroll
    for (int t = 0; t < 16; t++) {
        float bv = bias[t * 16 + m];
#pragma unroll
        for (int r = 0; r < 4; r++) {
            out[(long long)(row0 + q * 4 + r) * C + t * 16 + m] = acc[t][r] + bv;
        }
    }
}

// ---------------- fallback (round-1 path, used only if ws too small) --------

__global__ void init_kernel(const float* __restrict__ x0, float* __restrict__ out) {
    long long i = (long long)blockIdx.x * blockDim.x + threadIdx.x;
    const long long n_node4 = (long long)N_NODES * C / 4;
    const long long n_tot4  = (long long)(N_NODES + N_EDGES) * C / 4;
    float4* o4 = (float4*)out;
    if (i < n_node4)      o4[i] = ((const float4*)x0)[i];
    else if (i < n_tot4)  o4[i] = make_float4(0.f, 0.f, 0.f, 0.f);
}

__global__ void scatter_add_kernel(const float* __restrict__ src,
                                   const int* __restrict__ src_idx,
                                   const int* __restrict__ dst_idx,
                                   float* __restrict__ dst) {
    int j    = blockIdx.x * (blockDim.x >> 6) + (threadIdx.x >> 6);
    int lane = threadIdx.x & 63;
    if (j >= NNZ) return;
    int s = src_idx[j];
    int d = dst_idx[j];
    const float4 v = *(const float4*)(src + (long long)s * C + lane * 4);
    float* dp = dst + (long long)d * C + lane * 4;
    atomicAdd(dp + 0, v.x); atomicAdd(dp + 1, v.y);
    atomicAdd(dp + 2, v.z); atomicAdd(dp + 3, v.w);
}

__global__ void gin_gemm_kernel(const float* __restrict__ W,
                                const float* __restrict__ b,
                                float* __restrict__ out) {
    int n = blockIdx.x;
    int t = threadIdx.x;
    __shared__ float xs[C];
    float* row = out + (long long)n * C;
    xs[t] = row[t];
    __syncthreads();
    float acc = b[t];
    const float* wrow = W + t * C;
#pragma unroll 8
    for (int k = 0; k < C; k += 4) {
        float4 xv = *(const float4*)(xs + k);
        float4 wv = *(const float4*)(wrow + k);
        acc = fmaf(xv.x, wv.x, acc); acc = fmaf(xv.y, wv.y, acc);
        acc = fmaf(xv.z, wv.z, acc); acc = fmaf(xv.w, wv.w, acc);
    }
    row[t] = acc;
}

// ---------------------------------------------------------------------------

extern "C" void kernel_launch(void* const* d_in, const int* in_sizes, int n_in,
                              void* d_out, int out_size, void* d_ws, size_t ws_size,
                              hipStream_t stream) {
    const float* x0       = (const float*)d_in[0];
    const int*   node_idx = (const int*)d_in[1];
    const int*   edge_idx = (const int*)d_in[2];
    const float* W        = (const float*)d_in[3];
    const float* b        = (const float*)d_in[4];
    float* out = (float*)d_out;
    float* x1  = out + (size_t)N_NODES * C;   // output 1 lives here

    // workspace layout (256B-aligned chunks)
    char* p = (char*)d_ws;
    size_t used = 0;
    auto alloc = [&](size_t bytes) {
        char* r = p + used;
        used += (bytes + 255) & ~(size_t)255;
        return r;
    };
    int* off_e  = (int*)alloc((N_EDGES + 1) * 4);
    int* off_n  = (int*)alloc((N_NODES + 1) * 4);
    int* cur_e  = (int*)alloc(N_EDGES * 4);
    int* cur_n  = (int*)alloc(N_NODES * 4);
    int* cnt_e  = (int*)alloc(N_EDGES * 4);
    int* cnt_n  = (int*)alloc(N_NODES * 4);
    int* perm_e = (int*)alloc((size_t)NNZ * 4);
    int* perm_n = (int*)alloc((size_t)NNZ * 4);
    unsigned short* Wb = (unsigned short*)alloc((size_t)C * C * 2);
    unsigned short* xm = (unsigned short*)alloc((size_t)N_NODES * C * 2);

    if (ws_size < used) {
        // fallback: round-1 atomic path
        long long tot4 = (long long)(N_NODES + N_EDGES) * C / 4;
        init_kernel<<<(int)((tot4 + 255) / 256), 256, 0, stream>>>(x0, out);
        int grid = NNZ / 4;
        scatter_add_kernel<<<grid, 256, 0, stream>>>(x0, node_idx, edge_idx, x1);
        scatter_add_kernel<<<grid, 256, 0, stream>>>(x1, edge_idx, node_idx, out);
        gin_gemm_kernel<<<N_NODES, 256, 0, stream>>>(W, b, out);
        return;
    }

    // 1) zero histograms
    hipMemsetAsync(cnt_e, 0, N_EDGES * 4, stream);
    hipMemsetAsync(cnt_n, 0, N_NODES * 4, stream);

    // 2) histogram
    hist_kernel<<<NNZ / 256, 256, 0, stream>>>(node_idx, edge_idx, cnt_n, cnt_e);

    // 3) exclusive scans (one block each)
    scan_exclusive<<<1, 1024, 0, stream>>>(cnt_e, off_e, N_EDGES);
    scan_exclusive<<<1, 1024, 0, stream>>>(cnt_n, off_n, N_NODES);

    // 4) cursors = copy of offsets
    hipMemcpyAsync(cur_e, off_e, N_EDGES * 4, hipMemcpyDeviceToDevice, stream);
    hipMemcpyAsync(cur_n, off_n, N_NODES * 4, hipMemcpyDeviceToDevice, stream);

    // 5) build permutations
    build_perm<<<NNZ / 256, 256, 0, stream>>>(node_idx, edge_idx, cur_e, cur_n, perm_e, perm_n);

    // 6) vertex->edge pull: x1 (fp32, exact, non-atomic)
    pull_edge<<<N_EDGES / 4, 256, 0, stream>>>(x0, off_e, perm_e, x1);

    // 7) edge->vertex pull + x0 add, emit bf16 xm
    pull_node<<<N_NODES / 4, 256, 0, stream>>>(x0, x1, off_n, perm_n, xm);

    // 8) W -> bf16
    wconvert<<<(C * C / 4) / 256, 256, 0, stream>>>(W, Wb);

    // 9) out0 = xm @ W^T + b  via MFMA
    int waves = N_NODES / 16;                 // 6250
    int blocks = (waves + 3) / 4;             // 4 waves/block
    mfma_gemm<<<blocks, 256, 0, stream>>>(xm, Wb, b, out);
}

// Round 3
// 635.877 us; speedup vs baseline: 13.0654x; 1.4395x over previous
//
#include <hip/hip_runtime.h>

#define N_NODES 100000
#define N_EDGES 50000
#define NNZ     800000
#define C       256

typedef short  bf16x8 __attribute__((ext_vector_type(8)));
typedef float  f32x4  __attribute__((ext_vector_type(4)));

static __device__ __forceinline__ unsigned short f2bf(float f) {
    unsigned int u = __float_as_uint(f);
    u += 0x7FFF + ((u >> 16) & 1);   // round-to-nearest-even
    return (unsigned short)(u >> 16);
}
static __device__ __forceinline__ float bf2f(unsigned short u) {
    return __uint_as_float(((unsigned int)u) << 16);
}

// ---------------- conversions ----------------

__global__ void x0_to_bf16(const float* __restrict__ x0, unsigned short* __restrict__ x0b) {
    size_t i = (size_t)blockIdx.x * blockDim.x + threadIdx.x;   // float4 index
    float4 v = ((const float4*)x0)[i];
    ushort4 o;
    o.x = f2bf(v.x); o.y = f2bf(v.y); o.z = f2bf(v.z); o.w = f2bf(v.w);
    ((ushort4*)x0b)[i] = o;
}

// ---------------- CSR construction ----------------

__global__ void hist_kernel(const int* __restrict__ node_idx,
                            const int* __restrict__ edge_idx,
                            int* __restrict__ cnt_n, int* __restrict__ cnt_e) {
    int j = blockIdx.x * blockDim.x + threadIdx.x;
    atomicAdd(&cnt_n[node_idx[j]], 1);
    atomicAdd(&cnt_e[edge_idx[j]], 1);
}

// pass 1: per-block (1024-elem) sums. n divisible by 4; grid covers ceil(n/1024).
__global__ void scan_partials(const int* __restrict__ cnt, int* __restrict__ partials, int n) {
    int tid = threadIdx.x, lane = tid & 63, wid = tid >> 6;
    int base = blockIdx.x * 1024 + tid * 4;
    int s = 0;
    if (base < n) { int4 v = *(const int4*)(cnt + base); s = v.x + v.y + v.z + v.w; }
#pragma unroll
    for (int o = 1; o < 64; o <<= 1) s += __shfl_down(s, o, 64);
    __shared__ int ws[4];
    if (lane == 0) ws[wid] = s;
    __syncthreads();
    if (tid == 0) partials[blockIdx.x] = ws[0] + ws[1] + ws[2] + ws[3];
}

// pass 2: single 128-thread block, exclusive scan of partials (nb <= 98) in place.
// Also writes off[n] = total (known: NNZ).
__global__ void scan_small(int* __restrict__ partials, int nb, int* __restrict__ off_last, int total) {
    int tid = threadIdx.x, lane = tid & 63, wid = tid >> 6;
    int v = (tid < nb) ? partials[tid] : 0;
    int incl = v;
#pragma unroll
    for (int s = 1; s < 64; s <<= 1) { int u = __shfl_up(incl, s, 64); if (lane >= s) incl += u; }
    __shared__ int wsum[2];
    if (lane == 63) wsum[wid] = incl;
    __syncthreads();
    int excl = incl - v + (wid == 1 ? wsum[0] : 0);
    if (tid < nb) partials[tid] = excl;
    if (tid == 0) *off_last = total;
}

// pass 3: full exclusive scan using block partial base.
__global__ void scan_final(const int* __restrict__ cnt, const int* __restrict__ partials,
                           int* __restrict__ off, int n) {
    int tid = threadIdx.x, lane = tid & 63, wid = tid >> 6;
    int base = blockIdx.x * 1024 + tid * 4;
    int v0 = 0, v1 = 0, v2 = 0, v3 = 0;
    if (base < n) { int4 v = *(const int4*)(cnt + base); v0 = v.x; v1 = v.y; v2 = v.z; v3 = v.w; }
    int tsum = v0 + v1 + v2 + v3;
    int incl = tsum;
#pragma unroll
    for (int s = 1; s < 64; s <<= 1) { int u = __shfl_up(incl, s, 64); if (lane >= s) incl += u; }
    __shared__ int ws[4], wexcl[4];
    if (lane == 63) ws[wid] = incl;
    __syncthreads();
    if (tid == 0) { int c = 0; for (int i = 0; i < 4; i++) { wexcl[i] = c; c += ws[i]; } }
    __syncthreads();
    if (base < n) {
        int b = partials[blockIdx.x] + wexcl[wid] + (incl - tsum);
        off[base]     = b;
        off[base + 1] = b + v0;
        off[base + 2] = b + v0 + v1;
        off[base + 3] = b + v0 + v1 + v2;
    }
}

__global__ void build_perm(const int* __restrict__ node_idx,
                           const int* __restrict__ edge_idx,
                           int* __restrict__ cur_e, int* __restrict__ cur_n,
                           int* __restrict__ perm_e, int* __restrict__ perm_n) {
    int j = blockIdx.x * blockDim.x + threadIdx.x;
    int ni = node_idx[j], ei = edge_idx[j];
    int pe = atomicAdd(&cur_e[ei], 1);
    perm_e[pe] = ni;
    int pn = atomicAdd(&cur_n[ni], 1);
    perm_n[pn] = ei;
}

// ---------------- segment-sum pulls ----------------

// x1[e] = sum x0b rows; writes fp32 x1 (output) and bf16 x1b (for pull_node).
// One wave per edge; lane covers 4 channels.
__global__ void pull_edge(const unsigned short* __restrict__ x0b,
                          const int* __restrict__ off, const int* __restrict__ perm,
                          float* __restrict__ x1, unsigned short* __restrict__ x1b) {
    int e = blockIdx.x * 4 + (threadIdx.x >> 6);
    int lane = threadIdx.x & 63;
    int s0 = off[e], s1 = off[e + 1];
    float a0 = 0, a1 = 0, a2 = 0, a3 = 0;
    float b0 = 0, b1 = 0, b2 = 0, b3 = 0;
    int k = s0;
    for (; k + 2 <= s1; k += 2) {
        int r0 = perm[k], r1 = perm[k + 1];
        ushort4 u0 = *(const ushort4*)(x0b + (size_t)r0 * C + lane * 4);
        ushort4 u1 = *(const ushort4*)(x0b + (size_t)r1 * C + lane * 4);
        a0 += bf2f(u0.x); a1 += bf2f(u0.y); a2 += bf2f(u0.z); a3 += bf2f(u0.w);
        b0 += bf2f(u1.x); b1 += bf2f(u1.y); b2 += bf2f(u1.z); b3 += bf2f(u1.w);
    }
    if (k < s1) {
        int r0 = perm[k];
        ushort4 u0 = *(const ushort4*)(x0b + (size_t)r0 * C + lane * 4);
        a0 += bf2f(u0.x); a1 += bf2f(u0.y); a2 += bf2f(u0.z); a3 += bf2f(u0.w);
    }
    a0 += b0; a1 += b1; a2 += b2; a3 += b3;
    *(float4*)(x1 + (size_t)e * C + lane * 4) = make_float4(a0, a1, a2, a3);
    ushort4 o; o.x = f2bf(a0); o.y = f2bf(a1); o.z = f2bf(a2); o.w = f2bf(a3);
    *(ushort4*)(x1b + (size_t)e * C + lane * 4) = o;
}

// xm[n] = bf16( x0[n] + sum x1b rows )
__global__ void pull_node(const float* __restrict__ x0, const unsigned short* __restrict__ x1b,
                          const int* __restrict__ off, const int* __restrict__ perm,
                          unsigned short* __restrict__ xm) {
    int n = blockIdx.x * 4 + (threadIdx.x >> 6);
    int lane = threadIdx.x & 63;
    int s0 = off[n], s1 = off[n + 1];
    const float4 x = *(const float4*)(x0 + (size_t)n * C + lane * 4);
    float a0 = x.x, a1 = x.y, a2 = x.z, a3 = x.w;
    float b0 = 0, b1 = 0, b2 = 0, b3 = 0;
    int k = s0;
    for (; k + 2 <= s1; k += 2) {
        int r0 = perm[k], r1 = perm[k + 1];
        ushort4 u0 = *(const ushort4*)(x1b + (size_t)r0 * C + lane * 4);
        ushort4 u1 = *(const ushort4*)(x1b + (size_t)r1 * C + lane * 4);
        a0 += bf2f(u0.x); a1 += bf2f(u0.y); a2 += bf2f(u0.z); a3 += bf2f(u0.w);
        b0 += bf2f(u1.x); b1 += bf2f(u1.y); b2 += bf2f(u1.z); b3 += bf2f(u1.w);
    }
    if (k < s1) {
        int r0 = perm[k];
        ushort4 u0 = *(const ushort4*)(x1b + (size_t)r0 * C + lane * 4);
        a0 += bf2f(u0.x); a1 += bf2f(u0.y); a2 += bf2f(u0.z); a3 += bf2f(u0.w);
    }
    a0 += b0; a1 += b1; a2 += b2; a3 += b3;
    ushort4 o; o.x = f2bf(a0); o.y = f2bf(a1); o.z = f2bf(a2); o.w = f2bf(a3);
    *(ushort4*)(xm + (size_t)n * C + lane * 4) = o;
}

// ---------------- MFMA GEMM v2: W-half staged in 64 KB LDS ----------------
// Block = 512 threads (8 waves), covers 128 rows x 128 cols. grid = 782 row-tiles x 2 halves.
// LDS holds pre-swizzled B-fragments: Bs[((t*8+s)*64+l)*8 + j] = W[colbase+16t+(l&15)][32s+8(l>>4)+j]
// so the compute loop is one ds_read_b128 per (t,s) at lane-consecutive 16B addresses.
__global__ __launch_bounds__(512) void mfma_gemm2(const unsigned short* __restrict__ xm,
                                                  const float* __restrict__ W,
                                                  const float* __restrict__ bias,
                                                  float* __restrict__ out) {
    __shared__ unsigned short Bs[8 * 8 * 64 * 8];   // 65536 B
    const int rt = blockIdx.x >> 1;
    const int colbase = (blockIdx.x & 1) * 128;
    const int tid = threadIdx.x;

    // stage + convert W half (fp32 -> bf16), 4096 x 16B entries, 8 per thread
    for (int i = tid; i < 4096; i += 512) {
        int t = i >> 9, s = (i >> 6) & 7, l = i & 63;
        int m = l & 15, q = l >> 4;
        const float* src = W + (size_t)(colbase + 16 * t + m) * C + 32 * s + 8 * q;
        float4 f0 = *(const float4*)(src);
        float4 f1 = *(const float4*)(src + 4);
        unsigned short* d = Bs + (size_t)i * 8;
        d[0] = f2bf(f0.x); d[1] = f2bf(f0.y); d[2] = f2bf(f0.z); d[3] = f2bf(f0.w);
        d[4] = f2bf(f1.x); d[5] = f2bf(f1.y); d[6] = f2bf(f1.z); d[7] = f2bf(f1.w);
    }

    const int w = tid >> 6, lane = tid & 63;
    const int m = lane & 15, q = lane >> 4;
    const int row = rt * 128 + w * 16 + m;
    const int arow = row < N_NODES ? row : N_NODES - 1;   // clamp tail (stores guarded)

    // preload all 8 A-frags (independent 16B loads, one drain)
    bf16x8 a[8];
    const unsigned short* ap = xm + (size_t)arow * C + q * 8;
#pragma unroll
    for (int s = 0; s < 8; s++) a[s] = *(const bf16x8*)(ap + 32 * s);

    __syncthreads();

    f32x4 acc[8];
#pragma unroll
    for (int t = 0; t < 8; t++) acc[t] = (f32x4){0.f, 0.f, 0.f, 0.f};

#pragma unroll
    for (int s = 0; s < 8; s++) {
#pragma unroll
        for (int t = 0; t < 8; t++) {
            bf16x8 b = *(const bf16x8*)(Bs + ((t * 8 + s) * 64 + lane) * 8);
            acc[t] = __builtin_amdgcn_mfma_f32_16x16x32_bf16(a[s], b, acc[t], 0, 0, 0);
        }
    }

    const int r0 = rt * 128 + w * 16 + q * 4;
#pragma unroll
    for (int t = 0; t < 8; t++) {
        float bv = bias[colbase + t * 16 + m];
#pragma unroll
        for (int r = 0; r < 4; r++) {
            int rr = r0 + r;
            if (rr < N_NODES)
                out[(size_t)rr * C + colbase + t * 16 + m] = acc[t][r] + bv;
        }
    }
}

// ---------------- fallback (round-1 path, used only if ws too small) --------

__global__ void init_kernel(const float* __restrict__ x0, float* __restrict__ out) {
    long long i = (long long)blockIdx.x * blockDim.x + threadIdx.x;
    const long long n_node4 = (long long)N_NODES * C / 4;
    const long long n_tot4  = (long long)(N_NODES + N_EDGES) * C / 4;
    float4* o4 = (float4*)out;
    if (i < n_node4)      o4[i] = ((const float4*)x0)[i];
    else if (i < n_tot4)  o4[i] = make_float4(0.f, 0.f, 0.f, 0.f);
}

__global__ void scatter_add_kernel(const float* __restrict__ src,
                                   const int* __restrict__ src_idx,
                                   const int* __restrict__ dst_idx,
                                   float* __restrict__ dst) {
    int j    = blockIdx.x * (blockDim.x >> 6) + (threadIdx.x >> 6);
    int lane = threadIdx.x & 63;
    if (j >= NNZ) return;
    int s = src_idx[j];
    int d = dst_idx[j];
    const float4 v = *(const float4*)(src + (long long)s * C + lane * 4);
    float* dp = dst + (long long)d * C + lane * 4;
    atomicAdd(dp + 0, v.x); atomicAdd(dp + 1, v.y);
    atomicAdd(dp + 2, v.z); atomicAdd(dp + 3, v.w);
}

__global__ void gin_gemm_kernel(const float* __restrict__ W,
                                const float* __restrict__ b,
                                float* __restrict__ out) {
    int n = blockIdx.x;
    int t = threadIdx.x;
    __shared__ float xs[C];
    float* row = out + (long long)n * C;
    xs[t] = row[t];
    __syncthreads();
    float acc = b[t];
    const float* wrow = W + t * C;
#pragma unroll 8
    for (int k = 0; k < C; k += 4) {
        float4 xv = *(const float4*)(xs + k);
        float4 wv = *(const float4*)(wrow + k);
        acc = fmaf(xv.x, wv.x, acc); acc = fmaf(xv.y, wv.y, acc);
        acc = fmaf(xv.z, wv.z, acc); acc = fmaf(xv.w, wv.w, acc);
    }
    row[t] = acc;
}

// ---------------------------------------------------------------------------

extern "C" void kernel_launch(void* const* d_in, const int* in_sizes, int n_in,
                              void* d_out, int out_size, void* d_ws, size_t ws_size,
                              hipStream_t stream) {
    const float* x0       = (const float*)d_in[0];
    const int*   node_idx = (const int*)d_in[1];
    const int*   edge_idx = (const int*)d_in[2];
    const float* W        = (const float*)d_in[3];
    const float* b        = (const float*)d_in[4];
    float* out = (float*)d_out;
    float* x1  = out + (size_t)N_NODES * C;   // output 1

    char* p = (char*)d_ws;
    size_t used = 0;
    auto alloc = [&](size_t bytes) {
        char* r = p + used;
        used += (bytes + 255) & ~(size_t)255;
        return r;
    };
    int* off_e  = (int*)alloc((N_EDGES + 1) * 4);
    int* off_n  = (int*)alloc((N_NODES + 1) * 4);
    int* cur_e  = (int*)alloc(N_EDGES * 4);
    int* cur_n  = (int*)alloc(N_NODES * 4);
    int* cnt_e  = (int*)alloc(N_EDGES * 4);
    int* cnt_n  = (int*)alloc(N_NODES * 4);
    int* part_e = (int*)alloc(128 * 4);
    int* part_n = (int*)alloc(128 * 4);
    int* perm_e = (int*)alloc((size_t)NNZ * 4);
    int* perm_n = (int*)alloc((size_t)NNZ * 4);
    unsigned short* x0b = (unsigned short*)alloc((size_t)N_NODES * C * 2);
    unsigned short* x1b = (unsigned short*)alloc((size_t)N_EDGES * C * 2);
    unsigned short* xm  = (unsigned short*)alloc((size_t)N_NODES * C * 2);

    if (ws_size < used) {
        long long tot4 = (long long)(N_NODES + N_EDGES) * C / 4;
        init_kernel<<<(int)((tot4 + 255) / 256), 256, 0, stream>>>(x0, out);
        int grid = NNZ / 4;
        scatter_add_kernel<<<grid, 256, 0, stream>>>(x0, node_idx, edge_idx, x1);
        scatter_add_kernel<<<grid, 256, 0, stream>>>(x1, edge_idx, node_idx, out);
        gin_gemm_kernel<<<N_NODES, 256, 0, stream>>>(W, b, out);
        return;
    }

    hipMemsetAsync(cnt_e, 0, N_EDGES * 4, stream);
    hipMemsetAsync(cnt_n, 0, N_NODES * 4, stream);

    // x0 -> bf16 (for gathers)
    x0_to_bf16<<<N_NODES * C / 4 / 256, 256, 0, stream>>>(x0, x0b);

    // histogram
    hist_kernel<<<NNZ / 256, 256, 0, stream>>>(node_idx, edge_idx, cnt_n, cnt_e);

    // hierarchical exclusive scans
    const int nb_e = (N_EDGES + 1023) / 1024;   // 49
    const int nb_n = (N_NODES + 1023) / 1024;   // 98
    scan_partials<<<nb_e, 256, 0, stream>>>(cnt_e, part_e, N_EDGES);
    scan_small<<<1, 128, 0, stream>>>(part_e, nb_e, off_e + N_EDGES, NNZ);
    scan_final<<<nb_e, 256, 0, stream>>>(cnt_e, part_e, off_e, N_EDGES);
    scan_partials<<<nb_n, 256, 0, stream>>>(cnt_n, part_n, N_NODES);
    scan_small<<<1, 128, 0, stream>>>(part_n, nb_n, off_n + N_NODES, NNZ);
    scan_final<<<nb_n, 256, 0, stream>>>(cnt_n, part_n, off_n, N_NODES);

    // cursors
    hipMemcpyAsync(cur_e, off_e, N_EDGES * 4, hipMemcpyDeviceToDevice, stream);
    hipMemcpyAsync(cur_n, off_n, N_NODES * 4, hipMemcpyDeviceToDevice, stream);

    // permutations
    build_perm<<<NNZ / 256, 256, 0, stream>>>(node_idx, edge_idx, cur_e, cur_n, perm_e, perm_n);

    // pulls
    pull_edge<<<N_EDGES / 4, 256, 0, stream>>>(x0b, off_e, perm_e, x1, x1b);
    pull_node<<<N_NODES / 4, 256, 0, stream>>>(x0, x1b, off_n, perm_n, xm);

    // GEMM: out0 = xm @ W^T + b
    const int row_tiles = (N_NODES + 127) / 128;   // 782
    mfma_gemm2<<<row_tiles * 2, 512, 0, stream>>>(xm, W, b, out);
}